// Round 6
// baseline (191.323 us; speedup 1.0000x reference)
//
#include <hip/hip_runtime.h>

// HDR+ align, 2-kernel version, round 9.
// Round-8 post-mortem: K2@512thr = 47us, Occupancy 35%, VALU 52%, HBM 7% --
// latency-bound serial chain; widening halved independent chains/CU and lost
// 5us. This round maximizes TLP instead: K2 block = ONE S0 tile (4096 blocks
// x 128 thr, 4.4KB LDS, LB(128,8)) running the full S3->S2->S1->S0 chain;
// coarse levels computed redundantly by sibling blocks (identical fp ops on
// identical data -> bitwise identical). 16 chains/CU vs round-1's 4.
// Constants: T=16, SR=4, PADD=1, SS=11, SSC=9, WIN=26, SW=0.1, GR=2, batch 4, 512x512.

#define NB 4
#define NPIX (NB * 512 * 512)

// Composite 1D tap of (normalized gaussian sigma=1 r=2) followed by avg-pool-2.
constexpr float H6[6] = {
    0.027244342f, 0.149345013f, 0.323410645f,
    0.323410645f, 0.149345013f, 0.027244342f
};

// ---------------------------------------------------------------------------
// K1: pyramid. One block = 4x4 region of L3 (covers 32x32 L0). Grid (16,16,8).
// LDS overlay (floats): patch[0..3839] s64, tmpH1[3840..5519] s28,
// l1[0..783] s28 (overlays dead patch), tmpH2[784..1119] s12,
// l2[1120..1263] s12, tmpH3[1264..1311] s4.  Total 5520 fl = 22.1 KB.
// (Byte-identical to the 112.29us-verified version.)
// ---------------------------------------------------------------------------
__global__ void __launch_bounds__(256, 4)
pyramid_kernel(const float* __restrict__ src, const float* __restrict__ dst,
               float* __restrict__ ws) {
    __shared__ float smem[5520];
    float* patch = smem;            // 60 rows, stride 64
    float* tmpH1 = smem + 3840;     // 60 rows, stride 28
    float* l1    = smem;            // 28 rows, stride 28
    float* tmpH2 = smem + 784;      // 28 rows, stride 12
    float* l2    = smem + 1120;     // 12 rows, stride 12
    float* tmpH3 = smem + 1264;     // 12 rows, stride 4

    float* sL1 = ws;
    float* dL1 = sL1 + 4 * 65536;
    float* sL2 = dL1 + 4 * 65536;
    float* dL2 = sL2 + 4 * 16384;
    float* sL3 = dL2 + 4 * 16384;
    float* dL3 = sL3 + 4 * 4096;

    const int bx = blockIdx.x, by = blockIdx.y, z = blockIdx.z;
    const int t = threadIdx.x;
    const float* in = (z < 4) ? (src + (size_t)z * 262144) : (dst + (size_t)(z - 4) * 262144);
    float* oL1 = ((z < 4) ? sL1 : dL1) + (size_t)(z & 3) * 65536;
    float* oL2 = ((z < 4) ? sL2 : dL2) + (size_t)(z & 3) * 16384;
    float* oL3 = ((z < 4) ? sL3 : dL3) + (size_t)(z & 3) * 4096;

    // P0: 60x60 L0 patch at (by*32-14, bx*32-14), zero OOB (conv zero-pad).
    {
        const int oy = by * 32 - 14, ox = bx * 32 - 14;
        for (int idx = t; idx < 3600; idx += 256) {
            int r = idx / 60, c = idx - r * 60;
            int gy = oy + r, gx = ox + c;
            float v = 0.f;
            if ((unsigned)gy < 512u && (unsigned)gx < 512u) v = in[gy * 512 + gx];
            patch[r * 64 + c] = v;
        }
    }
    __syncthreads();
    // P1: horizontal -> tmpH1[60][28]
    for (int idx = t; idx < 1680; idx += 256) {
        int r = idx / 28, v = idx - r * 28;
        const float* p = &patch[r * 64 + 2 * v];
        float a = 0.f;
        #pragma unroll
        for (int bq = 0; bq < 6; ++bq) a = fmaf(H6[bq], p[bq], a);
        tmpH1[r * 28 + v] = a;
    }
    __syncthreads();
    // P2: vertical -> l1[28][28]; zero if L1 coord OOB (per-level zero-pad).
    {
        const int oy = by * 16 - 6, ox = bx * 16 - 6;
        for (int idx = t; idx < 784; idx += 256) {
            int u = idx / 28, v = idx - u * 28;
            float a = 0.f;
            int y1 = oy + u, x1 = ox + v;
            if ((unsigned)y1 < 256u && (unsigned)x1 < 256u) {
                #pragma unroll
                for (int bq = 0; bq < 6; ++bq) a = fmaf(H6[bq], tmpH1[(2 * u + bq) * 28 + v], a);
            }
            l1[u * 28 + v] = a;
        }
    }
    __syncthreads();
    // P3: write canonical L1 16x16 + horizontal -> tmpH2[28][12]
    {
        int u = t >> 4, v = t & 15;
        oL1[(by * 16 + u) * 256 + bx * 16 + v] = l1[(6 + u) * 28 + 6 + v];
    }
    for (int idx = t; idx < 336; idx += 256) {
        int r = idx / 12, v = idx - r * 12;
        const float* p = &l1[r * 28 + 2 * v];
        float a = 0.f;
        #pragma unroll
        for (int bq = 0; bq < 6; ++bq) a = fmaf(H6[bq], p[bq], a);
        tmpH2[r * 12 + v] = a;
    }
    __syncthreads();
    // P4: vertical -> l2[12][12]; zero if L2 coord OOB.
    {
        const int oy = by * 8 - 2, ox = bx * 8 - 2;
        if (t < 144) {
            int u = t / 12, v = t - u * 12;
            float a = 0.f;
            int y2 = oy + u, x2 = ox + v;
            if ((unsigned)y2 < 128u && (unsigned)x2 < 128u) {
                #pragma unroll
                for (int bq = 0; bq < 6; ++bq) a = fmaf(H6[bq], tmpH2[(2 * u + bq) * 12 + v], a);
            }
            l2[u * 12 + v] = a;
        }
    }
    __syncthreads();
    // P5: write canonical L2 8x8 + horizontal -> tmpH3[12][4]
    if (t < 64) {
        int u = t >> 3, v = t & 7;
        oL2[(by * 8 + u) * 128 + bx * 8 + v] = l2[(2 + u) * 12 + 2 + v];
    } else if (t < 112) {
        int idx = t - 64;
        int r = idx >> 2, v = idx & 3;
        const float* p = &l2[r * 12 + 2 * v];
        float a = 0.f;
        #pragma unroll
        for (int bq = 0; bq < 6; ++bq) a = fmaf(H6[bq], p[bq], a);
        tmpH3[r * 4 + v] = a;
    }
    __syncthreads();
    // P6: vertical -> L3 4x4, write global.
    if (t < 16) {
        int u = t >> 2, v = t & 3;
        float a = 0.f;
        #pragma unroll
        for (int bq = 0; bq < 6; ++bq) a = fmaf(H6[bq], tmpH3[(2 * u + bq) * 4 + v], a);
        oL3[(by * 4 + u) * 64 + bx * 4 + v] = a;
    }
}

// ---------------------------------------------------------------------------
// K2 helper: one block-matching level at cohort width 128 (2 waves).
// 2 SSD rows/lane, 8-lane dy-groups. Exactly 2 barriers per call.
// Result (oy, ox, od) is computed redundantly by EVERY lane (identical fp ops
// on identical LDS data -> bitwise identical) so offsets live in registers.
// (This is the proven FULL=false path from the 112.29us version.)
// ---------------------------------------------------------------------------
__device__ __forceinline__ void do_level(const float* __restrict__ simg,
                                         const float* __restrict__ dimg, int H,
                                         int ty, int tx, float pary, float parx, bool first,
                                         float* win, float* st, float* dist, int lt,
                                         float& roy, float& rox, float& rod) {
    float dyf = 0.f, dxf = 0.f;
    if (!first) {
        float iy = (float)(ty * 16), ix = (float)(tx * 16);
        // _inherit: round(clip(2*par + i, 0, H-16) - i), half-to-even (rintf).
        dyf = rintf(fminf(fmaxf(2.f * pary + iy, 0.f), (float)(H - 16)) - iy);
        dxf = rintf(fminf(fmaxf(2.f * parx + ix, 0.f), (float)(H - 16)) - ix);
    }
    const int ioy = (int)dyf, iox = (int)dxf;
    const int y0 = ty * 16 + ioy - 5;
    const int x0 = tx * 16 + iox - 5;

    for (int idx = lt; idx < 676; idx += 128) {
        int r = idx / 26, c = idx - r * 26;
        int gy = min(max(y0 + r, 0), H - 1);
        int gx = min(max(x0 + c, 0), H - 1);
        win[r * 28 + c] = dimg[gy * H + gx];
    }
    if (lt < 64) {
        int r = lt >> 2, q = lt & 3;
        const float4* srow = (const float4*)(simg + (size_t)(ty * 16 + r) * H + tx * 16);
        ((float4*)&st[r * 16])[q] = srow[q];
    }
    __syncthreads();   // B1

    const int dy = lt >> 3;
    if (dy < 11) {
        float acc[11];
        #pragma unroll
        for (int q = 0; q < 11; ++q) acc[q] = 0.f;
        #pragma unroll
        for (int rr = 0; rr < 2; ++rr) {
            const int i = (lt & 7) * 2 + rr;
            float w[28], s[16];
            const float4* wp = (const float4*)&win[(dy + i) * 28];
            #pragma unroll
            for (int q = 0; q < 7; ++q) ((float4*)w)[q] = wp[q];
            const float4* sp = (const float4*)&st[i * 16];
            #pragma unroll
            for (int q = 0; q < 4; ++q) ((float4*)s)[q] = sp[q];
            #pragma unroll
            for (int dx = 0; dx < 11; ++dx) {
                #pragma unroll
                for (int j = 0; j < 16; ++j) {
                    float d = w[dx + j] - s[j];
                    acc[dx] = fmaf(d, d, acc[dx]);
                }
            }
        }
        // reduce over 8-lane row groups (within-wave shfl_xor)
        #pragma unroll
        for (int m = 1; m <= 4; m <<= 1) {
            #pragma unroll
            for (int dx = 0; dx < 11; ++dx) acc[dx] += __shfl_xor(acc[dx], m);
        }
        if ((lt & 7) == 0) {
            float ay = (float)(dy - 5) * (1.f / 11.f);
            #pragma unroll
            for (int dx = 0; dx < 11; ++dx) {
                float ax = (float)(dx - 5) * (1.f / 11.f);
                dist[dy * 11 + dx] = acc[dx] * (1.f / 256.f) + 0.1f * (ay * ay + ax * ax);
            }
        }
    }
    __syncthreads();   // B2

    // Redundant per-lane argmin over central 9x9 (first occurrence on ties).
    const int l = lt & 63;
    float bv; int bk;
    {
        int k = l;                                    // 0..63 < 81 always
        int py = k / 9, px = k - (k / 9) * 9;
        bv = dist[(py + 1) * 11 + (px + 1)]; bk = k;
        k = l + 64;
        if (k < 81) {
            py = k / 9; px = k - (k / 9) * 9;
            float d = dist[(py + 1) * 11 + (px + 1)];
            if (d < bv) { bv = d; bk = k; }           // strict: tie keeps smaller k
        }
    }
    #pragma unroll
    for (int m = 1; m <= 32; m <<= 1) {
        float ov = __shfl_xor(bv, m);
        int   ok = __shfl_xor(bk, m);
        if (ov < bv || (ov == bv && ok < bk)) { bv = ov; bk = ok; }
    }
    // Redundant per-lane subpixel refine (broadcast LDS reads).
    {
        int py = bk / 9, px = bk - (bk / 9) * 9;
        float y00 = dist[(py + 0) * 11 + (px + 0)], y01 = dist[(py + 0) * 11 + (px + 1)], y02 = dist[(py + 0) * 11 + (px + 2)];
        float y10 = dist[(py + 1) * 11 + (px + 0)], y11 = dist[(py + 1) * 11 + (px + 1)], y12 = dist[(py + 1) * 11 + (px + 2)];
        float y20 = dist[(py + 2) * 11 + (px + 0)], y21 = dist[(py + 2) * 11 + (px + 1)], y22 = dist[(py + 2) * 11 + (px + 2)];

        float a11 = (y00 - 2.f * y01 + y02 + 2.f * y10 - 4.f * y11 + 2.f * y12 + y20 - 2.f * y21 + y22) * 0.25f;
        a11 = fmaxf(a11, 0.f);
        float a22 = (y00 + 2.f * y01 + y02 - 2.f * y10 - 4.f * y11 - 2.f * y12 + y20 + 2.f * y21 + y22) * 0.25f;
        a22 = fmaxf(a22, 0.f);
        float a12 = (y00 - y02 - y20 + y22) * 0.25f;
        float b1  = (-y00 + y02 - 2.f * y10 + 2.f * y12 - y20 + y22) * 0.125f;
        float b2  = (-y00 - 2.f * y01 - y02 + y20 + 2.f * y21 + y22) * 0.125f;

        float det  = a11 * a22 - a12 * a12;
        float a12z = (det < 0.f) ? 0.f : a12;
        float mu_x = -(a22 * b1 - a12z * b2) / det;   // inf/nan when det==0 -> filtered
        float mu_y = -(a11 * b2 - a12z * b1) / det;
        float mu_len = sqrtf(mu_x * mu_x + mu_y * mu_y);
        float addx = (mu_len < 1.f) ? mu_x : 0.f;     // NaN -> false, matches jnp.where
        float addy = (mu_len < 1.f) ? mu_y : 0.f;

        roy = dyf + (float)(py - 4) + addy;
        rox = dxf + (float)(px - 4) + addx;
        rod = bv;
    }
}

// ---------------------------------------------------------------------------
// K2: one block per S0 tile (4096 blocks, 128 thr = 2 waves). Each block runs
// the full chain S3->S2->S1->S0; coarse rounds are computed redundantly by
// sibling blocks (bitwise-identical results). LDS 1112 fl = 4.4 KB.
// LB(128,8): 8 waves/SIMD -> 16 blocks/CU co-resident = 16 independent
// latency chains per CU (vs 4 in the 112us version, 2 in round 8).
// ---------------------------------------------------------------------------
__global__ void __launch_bounds__(128, 8)
step_chain_kernel(const float* __restrict__ src, const float* __restrict__ dst,
                  const float* __restrict__ ws, float* __restrict__ out) {
    __shared__ float smem[1112];    // win[728] ++ st[256] ++ dist[128]
    float* win  = smem;
    float* st   = smem + 728;
    float* dist = smem + 984;

    const float* sL1 = ws;
    const float* dL1 = sL1 + 4 * 65536;
    const float* sL2 = dL1 + 4 * 65536;
    const float* dL2 = sL2 + 4 * 16384;
    const float* sL3 = dL2 + 4 * 16384;
    const float* dL3 = sL3 + 4 * 4096;

    const int gid = blockIdx.x;
    const int b   = gid >> 10;
    const int ty0 = (gid >> 5) & 31;
    const int tx0 = gid & 31;
    const int t   = threadIdx.x;

    const float* s0 = src + (size_t)b * 262144; const float* d0 = dst + (size_t)b * 262144;
    const float* s1 = sL1 + (size_t)b * 65536;  const float* d1 = dL1 + (size_t)b * 65536;
    const float* s2 = sL2 + (size_t)b * 16384;  const float* d2 = dL2 + (size_t)b * 16384;
    const float* s3 = sL3 + (size_t)b * 4096;   const float* d3 = dL3 + (size_t)b * 4096;

    float oy, ox, od;
    do_level(s3, d3,  64, ty0 >> 3, tx0 >> 3, 0.f, 0.f, true,
             win, st, dist, t, oy, ox, od);
    do_level(s2, d2, 128, ty0 >> 2, tx0 >> 2, oy, ox, false,
             win, st, dist, t, oy, ox, od);
    do_level(s1, d1, 256, ty0 >> 1, tx0 >> 1, oy, ox, false,
             win, st, dist, t, oy, ox, od);
    do_level(s0, d0, 512, ty0,      tx0,      oy, ox, false,
             win, st, dist, t, oy, ox, od);

    // Fused expand: every lane holds identical (oy,ox,od). 16x16 px, 2/lane.
    int r = t >> 3, c = (t & 7) * 2;
    int pyy = ty0 * 16 + r, pxx = tx0 * 16 + c;
    size_t pi = ((size_t)(b * 512 + pyy)) * 512 + pxx;
    float2 o; o.x = oy; o.y = ox;
    ((float2*)out)[pi]     = o;
    ((float2*)out)[pi + 1] = o;
    float2 dd; dd.x = od; dd.y = od;
    *(float2*)(out + (size_t)NPIX * 2 + pi) = dd;
}

extern "C" void kernel_launch(void* const* d_in, const int* in_sizes, int n_in,
                              void* d_out, int out_size, void* d_ws, size_t ws_size,
                              hipStream_t stream) {
    const float* src = (const float*)d_in[0];   // (4,1,512,512)
    const float* dst = (const float*)d_in[1];   // (4,1,512,512)
    float* out = (float*)d_out;                  // offsets (NPIX*2) ++ dist (NPIX)
    float* ws  = (float*)d_ws;                   // pyramid levels, 2.75 MB

    hipLaunchKernelGGL(pyramid_kernel, dim3(16, 16, 8), dim3(256), 0, stream, src, dst, ws);
    hipLaunchKernelGGL(step_chain_kernel, dim3(4096), dim3(128), 0, stream, src, dst, ws, out);
}

// Round 7
// 141.559 us; speedup vs baseline: 1.3515x; 1.3515x over previous
//
#include <hip/hip_runtime.h>

// HDR+ align, 2-kernel version, round 10.
// Round-9 post-mortem: LB(128,8) capped VGPR at 32 -> do_level's w[28]/s[16]/
// acc[11] spilled to scratch (WRITE_SIZE 248MB vs 12.6MB logical, K2 118us).
// Fix: LB(128,4) -> 128-VGPR cap (same code compiled to 64 VGPR under this
// cap in round 8, zero spill). Runtime occupancy still 6-8 waves/EU at ~64
// VGPR -> 12-16 independent chains/CU. Structure unchanged: one block per S0
// tile (4096 x 128), full S3->S2->S1->S0 chain, coarse levels redundantly
// computed by sibling blocks (bitwise identical).
// Constants: T=16, SR=4, PADD=1, SS=11, SSC=9, WIN=26, SW=0.1, GR=2, batch 4, 512x512.

#define NB 4
#define NPIX (NB * 512 * 512)

// Composite 1D tap of (normalized gaussian sigma=1 r=2) followed by avg-pool-2.
constexpr float H6[6] = {
    0.027244342f, 0.149345013f, 0.323410645f,
    0.323410645f, 0.149345013f, 0.027244342f
};

// ---------------------------------------------------------------------------
// K1: pyramid. One block = 4x4 region of L3 (covers 32x32 L0). Grid (16,16,8).
// LDS overlay (floats): patch[0..3839] s64, tmpH1[3840..5519] s28,
// l1[0..783] s28 (overlays dead patch), tmpH2[784..1119] s12,
// l2[1120..1263] s12, tmpH3[1264..1311] s4.  Total 5520 fl = 22.1 KB.
// (Byte-identical to the 112.29us-verified version.)
// ---------------------------------------------------------------------------
__global__ void __launch_bounds__(256, 4)
pyramid_kernel(const float* __restrict__ src, const float* __restrict__ dst,
               float* __restrict__ ws) {
    __shared__ float smem[5520];
    float* patch = smem;            // 60 rows, stride 64
    float* tmpH1 = smem + 3840;     // 60 rows, stride 28
    float* l1    = smem;            // 28 rows, stride 28
    float* tmpH2 = smem + 784;      // 28 rows, stride 12
    float* l2    = smem + 1120;     // 12 rows, stride 12
    float* tmpH3 = smem + 1264;     // 12 rows, stride 4

    float* sL1 = ws;
    float* dL1 = sL1 + 4 * 65536;
    float* sL2 = dL1 + 4 * 65536;
    float* dL2 = sL2 + 4 * 16384;
    float* sL3 = dL2 + 4 * 16384;
    float* dL3 = sL3 + 4 * 4096;

    const int bx = blockIdx.x, by = blockIdx.y, z = blockIdx.z;
    const int t = threadIdx.x;
    const float* in = (z < 4) ? (src + (size_t)z * 262144) : (dst + (size_t)(z - 4) * 262144);
    float* oL1 = ((z < 4) ? sL1 : dL1) + (size_t)(z & 3) * 65536;
    float* oL2 = ((z < 4) ? sL2 : dL2) + (size_t)(z & 3) * 16384;
    float* oL3 = ((z < 4) ? sL3 : dL3) + (size_t)(z & 3) * 4096;

    // P0: 60x60 L0 patch at (by*32-14, bx*32-14), zero OOB (conv zero-pad).
    {
        const int oy = by * 32 - 14, ox = bx * 32 - 14;
        for (int idx = t; idx < 3600; idx += 256) {
            int r = idx / 60, c = idx - r * 60;
            int gy = oy + r, gx = ox + c;
            float v = 0.f;
            if ((unsigned)gy < 512u && (unsigned)gx < 512u) v = in[gy * 512 + gx];
            patch[r * 64 + c] = v;
        }
    }
    __syncthreads();
    // P1: horizontal -> tmpH1[60][28]
    for (int idx = t; idx < 1680; idx += 256) {
        int r = idx / 28, v = idx - r * 28;
        const float* p = &patch[r * 64 + 2 * v];
        float a = 0.f;
        #pragma unroll
        for (int bq = 0; bq < 6; ++bq) a = fmaf(H6[bq], p[bq], a);
        tmpH1[r * 28 + v] = a;
    }
    __syncthreads();
    // P2: vertical -> l1[28][28]; zero if L1 coord OOB (per-level zero-pad).
    {
        const int oy = by * 16 - 6, ox = bx * 16 - 6;
        for (int idx = t; idx < 784; idx += 256) {
            int u = idx / 28, v = idx - u * 28;
            float a = 0.f;
            int y1 = oy + u, x1 = ox + v;
            if ((unsigned)y1 < 256u && (unsigned)x1 < 256u) {
                #pragma unroll
                for (int bq = 0; bq < 6; ++bq) a = fmaf(H6[bq], tmpH1[(2 * u + bq) * 28 + v], a);
            }
            l1[u * 28 + v] = a;
        }
    }
    __syncthreads();
    // P3: write canonical L1 16x16 + horizontal -> tmpH2[28][12]
    {
        int u = t >> 4, v = t & 15;
        oL1[(by * 16 + u) * 256 + bx * 16 + v] = l1[(6 + u) * 28 + 6 + v];
    }
    for (int idx = t; idx < 336; idx += 256) {
        int r = idx / 12, v = idx - r * 12;
        const float* p = &l1[r * 28 + 2 * v];
        float a = 0.f;
        #pragma unroll
        for (int bq = 0; bq < 6; ++bq) a = fmaf(H6[bq], p[bq], a);
        tmpH2[r * 12 + v] = a;
    }
    __syncthreads();
    // P4: vertical -> l2[12][12]; zero if L2 coord OOB.
    {
        const int oy = by * 8 - 2, ox = bx * 8 - 2;
        if (t < 144) {
            int u = t / 12, v = t - u * 12;
            float a = 0.f;
            int y2 = oy + u, x2 = ox + v;
            if ((unsigned)y2 < 128u && (unsigned)x2 < 128u) {
                #pragma unroll
                for (int bq = 0; bq < 6; ++bq) a = fmaf(H6[bq], tmpH2[(2 * u + bq) * 12 + v], a);
            }
            l2[u * 12 + v] = a;
        }
    }
    __syncthreads();
    // P5: write canonical L2 8x8 + horizontal -> tmpH3[12][4]
    if (t < 64) {
        int u = t >> 3, v = t & 7;
        oL2[(by * 8 + u) * 128 + bx * 8 + v] = l2[(2 + u) * 12 + 2 + v];
    } else if (t < 112) {
        int idx = t - 64;
        int r = idx >> 2, v = idx & 3;
        const float* p = &l2[r * 12 + 2 * v];
        float a = 0.f;
        #pragma unroll
        for (int bq = 0; bq < 6; ++bq) a = fmaf(H6[bq], p[bq], a);
        tmpH3[r * 4 + v] = a;
    }
    __syncthreads();
    // P6: vertical -> L3 4x4, write global.
    if (t < 16) {
        int u = t >> 2, v = t & 3;
        float a = 0.f;
        #pragma unroll
        for (int bq = 0; bq < 6; ++bq) a = fmaf(H6[bq], tmpH3[(2 * u + bq) * 4 + v], a);
        oL3[(by * 4 + u) * 64 + bx * 4 + v] = a;
    }
}

// ---------------------------------------------------------------------------
// K2 helper: one block-matching level at cohort width 128 (2 waves).
// 2 SSD rows/lane, 8-lane dy-groups. Exactly 2 barriers per call.
// Result (oy, ox, od) is computed redundantly by EVERY lane (identical fp ops
// on identical LDS data -> bitwise identical) so offsets live in registers.
// ---------------------------------------------------------------------------
__device__ __forceinline__ void do_level(const float* __restrict__ simg,
                                         const float* __restrict__ dimg, int H,
                                         int ty, int tx, float pary, float parx, bool first,
                                         float* win, float* st, float* dist, int lt,
                                         float& roy, float& rox, float& rod) {
    float dyf = 0.f, dxf = 0.f;
    if (!first) {
        float iy = (float)(ty * 16), ix = (float)(tx * 16);
        // _inherit: round(clip(2*par + i, 0, H-16) - i), half-to-even (rintf).
        dyf = rintf(fminf(fmaxf(2.f * pary + iy, 0.f), (float)(H - 16)) - iy);
        dxf = rintf(fminf(fmaxf(2.f * parx + ix, 0.f), (float)(H - 16)) - ix);
    }
    const int ioy = (int)dyf, iox = (int)dxf;
    const int y0 = ty * 16 + ioy - 5;
    const int x0 = tx * 16 + iox - 5;

    for (int idx = lt; idx < 676; idx += 128) {
        int r = idx / 26, c = idx - r * 26;
        int gy = min(max(y0 + r, 0), H - 1);
        int gx = min(max(x0 + c, 0), H - 1);
        win[r * 28 + c] = dimg[gy * H + gx];
    }
    if (lt < 64) {
        int r = lt >> 2, q = lt & 3;
        const float4* srow = (const float4*)(simg + (size_t)(ty * 16 + r) * H + tx * 16);
        ((float4*)&st[r * 16])[q] = srow[q];
    }
    __syncthreads();   // B1

    const int dy = lt >> 3;
    if (dy < 11) {
        float acc[11];
        #pragma unroll
        for (int q = 0; q < 11; ++q) acc[q] = 0.f;
        #pragma unroll
        for (int rr = 0; rr < 2; ++rr) {
            const int i = (lt & 7) * 2 + rr;
            float w[28], s[16];
            const float4* wp = (const float4*)&win[(dy + i) * 28];
            #pragma unroll
            for (int q = 0; q < 7; ++q) ((float4*)w)[q] = wp[q];
            const float4* sp = (const float4*)&st[i * 16];
            #pragma unroll
            for (int q = 0; q < 4; ++q) ((float4*)s)[q] = sp[q];
            #pragma unroll
            for (int dx = 0; dx < 11; ++dx) {
                #pragma unroll
                for (int j = 0; j < 16; ++j) {
                    float d = w[dx + j] - s[j];
                    acc[dx] = fmaf(d, d, acc[dx]);
                }
            }
        }
        // reduce over 8-lane row groups (within-wave shfl_xor)
        #pragma unroll
        for (int m = 1; m <= 4; m <<= 1) {
            #pragma unroll
            for (int dx = 0; dx < 11; ++dx) acc[dx] += __shfl_xor(acc[dx], m);
        }
        if ((lt & 7) == 0) {
            float ay = (float)(dy - 5) * (1.f / 11.f);
            #pragma unroll
            for (int dx = 0; dx < 11; ++dx) {
                float ax = (float)(dx - 5) * (1.f / 11.f);
                dist[dy * 11 + dx] = acc[dx] * (1.f / 256.f) + 0.1f * (ay * ay + ax * ax);
            }
        }
    }
    __syncthreads();   // B2

    // Redundant per-lane argmin over central 9x9 (first occurrence on ties).
    const int l = lt & 63;
    float bv; int bk;
    {
        int k = l;                                    // 0..63 < 81 always
        int py = k / 9, px = k - (k / 9) * 9;
        bv = dist[(py + 1) * 11 + (px + 1)]; bk = k;
        k = l + 64;
        if (k < 81) {
            py = k / 9; px = k - (k / 9) * 9;
            float d = dist[(py + 1) * 11 + (px + 1)];
            if (d < bv) { bv = d; bk = k; }           // strict: tie keeps smaller k
        }
    }
    #pragma unroll
    for (int m = 1; m <= 32; m <<= 1) {
        float ov = __shfl_xor(bv, m);
        int   ok = __shfl_xor(bk, m);
        if (ov < bv || (ov == bv && ok < bk)) { bv = ov; bk = ok; }
    }
    // Redundant per-lane subpixel refine (broadcast LDS reads).
    {
        int py = bk / 9, px = bk - (bk / 9) * 9;
        float y00 = dist[(py + 0) * 11 + (px + 0)], y01 = dist[(py + 0) * 11 + (px + 1)], y02 = dist[(py + 0) * 11 + (px + 2)];
        float y10 = dist[(py + 1) * 11 + (px + 0)], y11 = dist[(py + 1) * 11 + (px + 1)], y12 = dist[(py + 1) * 11 + (px + 2)];
        float y20 = dist[(py + 2) * 11 + (px + 0)], y21 = dist[(py + 2) * 11 + (px + 1)], y22 = dist[(py + 2) * 11 + (px + 2)];

        float a11 = (y00 - 2.f * y01 + y02 + 2.f * y10 - 4.f * y11 + 2.f * y12 + y20 - 2.f * y21 + y22) * 0.25f;
        a11 = fmaxf(a11, 0.f);
        float a22 = (y00 + 2.f * y01 + y02 - 2.f * y10 - 4.f * y11 - 2.f * y12 + y20 + 2.f * y21 + y22) * 0.25f;
        a22 = fmaxf(a22, 0.f);
        float a12 = (y00 - y02 - y20 + y22) * 0.25f;
        float b1  = (-y00 + y02 - 2.f * y10 + 2.f * y12 - y20 + y22) * 0.125f;
        float b2  = (-y00 - 2.f * y01 - y02 + y20 + 2.f * y21 + y22) * 0.125f;

        float det  = a11 * a22 - a12 * a12;
        float a12z = (det < 0.f) ? 0.f : a12;
        float mu_x = -(a22 * b1 - a12z * b2) / det;   // inf/nan when det==0 -> filtered
        float mu_y = -(a11 * b2 - a12z * b1) / det;
        float mu_len = sqrtf(mu_x * mu_x + mu_y * mu_y);
        float addx = (mu_len < 1.f) ? mu_x : 0.f;     // NaN -> false, matches jnp.where
        float addy = (mu_len < 1.f) ? mu_y : 0.f;

        roy = dyf + (float)(py - 4) + addy;
        rox = dxf + (float)(px - 4) + addx;
        rod = bv;
    }
}

// ---------------------------------------------------------------------------
// K2: one block per S0 tile (4096 blocks, 128 thr = 2 waves). Each block runs
// the full chain S3->S2->S1->S0; coarse rounds are computed redundantly by
// sibling blocks (bitwise-identical results). LDS 1112 fl = 4.4 KB.
// LB(128,4): 128-VGPR cap -- do_level fits in ~64 VGPR (round-8 evidence),
// NO spill; runtime occupancy 6-8 waves/EU -> 12-16 chains/CU.
// ---------------------------------------------------------------------------
__global__ void __launch_bounds__(128, 4)
step_chain_kernel(const float* __restrict__ src, const float* __restrict__ dst,
                  const float* __restrict__ ws, float* __restrict__ out) {
    __shared__ float smem[1112];    // win[728] ++ st[256] ++ dist[128]
    float* win  = smem;
    float* st   = smem + 728;
    float* dist = smem + 984;

    const float* sL1 = ws;
    const float* dL1 = sL1 + 4 * 65536;
    const float* sL2 = dL1 + 4 * 65536;
    const float* dL2 = sL2 + 4 * 16384;
    const float* sL3 = dL2 + 4 * 16384;
    const float* dL3 = sL3 + 4 * 4096;

    const int gid = blockIdx.x;
    const int b   = gid >> 10;
    const int ty0 = (gid >> 5) & 31;
    const int tx0 = gid & 31;
    const int t   = threadIdx.x;

    const float* s0 = src + (size_t)b * 262144; const float* d0 = dst + (size_t)b * 262144;
    const float* s1 = sL1 + (size_t)b * 65536;  const float* d1 = dL1 + (size_t)b * 65536;
    const float* s2 = sL2 + (size_t)b * 16384;  const float* d2 = dL2 + (size_t)b * 16384;
    const float* s3 = sL3 + (size_t)b * 4096;   const float* d3 = dL3 + (size_t)b * 4096;

    float oy, ox, od;
    do_level(s3, d3,  64, ty0 >> 3, tx0 >> 3, 0.f, 0.f, true,
             win, st, dist, t, oy, ox, od);
    do_level(s2, d2, 128, ty0 >> 2, tx0 >> 2, oy, ox, false,
             win, st, dist, t, oy, ox, od);
    do_level(s1, d1, 256, ty0 >> 1, tx0 >> 1, oy, ox, false,
             win, st, dist, t, oy, ox, od);
    do_level(s0, d0, 512, ty0,      tx0,      oy, ox, false,
             win, st, dist, t, oy, ox, od);

    // Fused expand: every lane holds identical (oy,ox,od). 16x16 px, 2/lane.
    int r = t >> 3, c = (t & 7) * 2;
    int pyy = ty0 * 16 + r, pxx = tx0 * 16 + c;
    size_t pi = ((size_t)(b * 512 + pyy)) * 512 + pxx;
    float2 o; o.x = oy; o.y = ox;
    ((float2*)out)[pi]     = o;
    ((float2*)out)[pi + 1] = o;
    float2 dd; dd.x = od; dd.y = od;
    *(float2*)(out + (size_t)NPIX * 2 + pi) = dd;
}

extern "C" void kernel_launch(void* const* d_in, const int* in_sizes, int n_in,
                              void* d_out, int out_size, void* d_ws, size_t ws_size,
                              hipStream_t stream) {
    const float* src = (const float*)d_in[0];   // (4,1,512,512)
    const float* dst = (const float*)d_in[1];   // (4,1,512,512)
    float* out = (float*)d_out;                  // offsets (NPIX*2) ++ dist (NPIX)
    float* ws  = (float*)d_ws;                   // pyramid levels, 2.75 MB

    hipLaunchKernelGGL(pyramid_kernel, dim3(16, 16, 8), dim3(256), 0, stream, src, dst, ws);
    hipLaunchKernelGGL(step_chain_kernel, dim3(4096), dim3(128), 0, stream, src, dst, ws, out);
}

// Round 8
// 122.400 us; speedup vs baseline: 1.5631x; 1.1565x over previous
//
#include <hip/hip_runtime.h>

// HDR+ align, 2-kernel version, round 11.
// Accounting: total = fill(~44us, harness ws poison) + K1(~20) + K2 + gaps.
// Baseline K2 (1024x256, shared coarse rounds) at ~42us was best; R8/R10
// restructures lost via fewer chains/CU or 2.3x redundant work. This round:
// baseline skeleton, but S0's two sequential half-rounds collapsed into ONE
// round of 4 wave-slots (64 thr each). Chain depth 5 -> 4, zero added
// redundancy, 4 blocks/CU unchanged.
// Constants: T=16, SR=4, PADD=1, SS=11, SSC=9, WIN=26, SW=0.1, GR=2, batch 4, 512x512.

#define NB 4
#define NPIX (NB * 512 * 512)

// Composite 1D tap of (normalized gaussian sigma=1 r=2) followed by avg-pool-2.
constexpr float H6[6] = {
    0.027244342f, 0.149345013f, 0.323410645f,
    0.323410645f, 0.149345013f, 0.027244342f
};

// ---------------------------------------------------------------------------
// K1: pyramid. One block = 4x4 region of L3 (covers 32x32 L0). Grid (16,16,8).
// LDS overlay (floats): patch[0..3839] s64, tmpH1[3840..5519] s28,
// l1[0..783] s28 (overlays dead patch), tmpH2[784..1119] s12,
// l2[1120..1263] s12, tmpH3[1264..1311] s4.  Total 5520 fl = 22.1 KB.
// (Byte-identical to the 112.29us-verified version.)
// ---------------------------------------------------------------------------
__global__ void __launch_bounds__(256, 4)
pyramid_kernel(const float* __restrict__ src, const float* __restrict__ dst,
               float* __restrict__ ws) {
    __shared__ float smem[5520];
    float* patch = smem;            // 60 rows, stride 64
    float* tmpH1 = smem + 3840;     // 60 rows, stride 28
    float* l1    = smem;            // 28 rows, stride 28
    float* tmpH2 = smem + 784;      // 28 rows, stride 12
    float* l2    = smem + 1120;     // 12 rows, stride 12
    float* tmpH3 = smem + 1264;     // 12 rows, stride 4

    float* sL1 = ws;
    float* dL1 = sL1 + 4 * 65536;
    float* sL2 = dL1 + 4 * 65536;
    float* dL2 = sL2 + 4 * 16384;
    float* sL3 = dL2 + 4 * 16384;
    float* dL3 = sL3 + 4 * 4096;

    const int bx = blockIdx.x, by = blockIdx.y, z = blockIdx.z;
    const int t = threadIdx.x;
    const float* in = (z < 4) ? (src + (size_t)z * 262144) : (dst + (size_t)(z - 4) * 262144);
    float* oL1 = ((z < 4) ? sL1 : dL1) + (size_t)(z & 3) * 65536;
    float* oL2 = ((z < 4) ? sL2 : dL2) + (size_t)(z & 3) * 16384;
    float* oL3 = ((z < 4) ? sL3 : dL3) + (size_t)(z & 3) * 4096;

    // P0: 60x60 L0 patch at (by*32-14, bx*32-14), zero OOB (conv zero-pad).
    {
        const int oy = by * 32 - 14, ox = bx * 32 - 14;
        for (int idx = t; idx < 3600; idx += 256) {
            int r = idx / 60, c = idx - r * 60;
            int gy = oy + r, gx = ox + c;
            float v = 0.f;
            if ((unsigned)gy < 512u && (unsigned)gx < 512u) v = in[gy * 512 + gx];
            patch[r * 64 + c] = v;
        }
    }
    __syncthreads();
    // P1: horizontal -> tmpH1[60][28]
    for (int idx = t; idx < 1680; idx += 256) {
        int r = idx / 28, v = idx - r * 28;
        const float* p = &patch[r * 64 + 2 * v];
        float a = 0.f;
        #pragma unroll
        for (int bq = 0; bq < 6; ++bq) a = fmaf(H6[bq], p[bq], a);
        tmpH1[r * 28 + v] = a;
    }
    __syncthreads();
    // P2: vertical -> l1[28][28]; zero if L1 coord OOB (per-level zero-pad).
    {
        const int oy = by * 16 - 6, ox = bx * 16 - 6;
        for (int idx = t; idx < 784; idx += 256) {
            int u = idx / 28, v = idx - u * 28;
            float a = 0.f;
            int y1 = oy + u, x1 = ox + v;
            if ((unsigned)y1 < 256u && (unsigned)x1 < 256u) {
                #pragma unroll
                for (int bq = 0; bq < 6; ++bq) a = fmaf(H6[bq], tmpH1[(2 * u + bq) * 28 + v], a);
            }
            l1[u * 28 + v] = a;
        }
    }
    __syncthreads();
    // P3: write canonical L1 16x16 + horizontal -> tmpH2[28][12]
    {
        int u = t >> 4, v = t & 15;
        oL1[(by * 16 + u) * 256 + bx * 16 + v] = l1[(6 + u) * 28 + 6 + v];
    }
    for (int idx = t; idx < 336; idx += 256) {
        int r = idx / 12, v = idx - r * 12;
        const float* p = &l1[r * 28 + 2 * v];
        float a = 0.f;
        #pragma unroll
        for (int bq = 0; bq < 6; ++bq) a = fmaf(H6[bq], p[bq], a);
        tmpH2[r * 12 + v] = a;
    }
    __syncthreads();
    // P4: vertical -> l2[12][12]; zero if L2 coord OOB.
    {
        const int oy = by * 8 - 2, ox = bx * 8 - 2;
        if (t < 144) {
            int u = t / 12, v = t - u * 12;
            float a = 0.f;
            int y2 = oy + u, x2 = ox + v;
            if ((unsigned)y2 < 128u && (unsigned)x2 < 128u) {
                #pragma unroll
                for (int bq = 0; bq < 6; ++bq) a = fmaf(H6[bq], tmpH2[(2 * u + bq) * 12 + v], a);
            }
            l2[u * 12 + v] = a;
        }
    }
    __syncthreads();
    // P5: write canonical L2 8x8 + horizontal -> tmpH3[12][4]
    if (t < 64) {
        int u = t >> 3, v = t & 7;
        oL2[(by * 8 + u) * 128 + bx * 8 + v] = l2[(2 + u) * 12 + 2 + v];
    } else if (t < 112) {
        int idx = t - 64;
        int r = idx >> 2, v = idx & 3;
        const float* p = &l2[r * 12 + 2 * v];
        float a = 0.f;
        #pragma unroll
        for (int bq = 0; bq < 6; ++bq) a = fmaf(H6[bq], p[bq], a);
        tmpH3[r * 4 + v] = a;
    }
    __syncthreads();
    // P6: vertical -> L3 4x4, write global.
    if (t < 16) {
        int u = t >> 2, v = t & 3;
        float a = 0.f;
        #pragma unroll
        for (int bq = 0; bq < 6; ++bq) a = fmaf(H6[bq], tmpH3[(2 * u + bq) * 4 + v], a);
        oL3[(by * 4 + u) * 64 + bx * 4 + v] = a;
    }
}

// ---------------------------------------------------------------------------
// K2 helper: one block-matching level at cohort width NL (256 full / 64 slot).
// G = NL/16 lanes per dy-group, ROWS = 16/G SSD rows per lane.
// NL=256: identical to the proven baseline FULL path (G=16, 1 row/lane).
// NL=64: wave-slot (G=4, 4 rows/lane) -- slots coincide with waves, so all
// shuffles stay in-wave. Exactly 2 block barriers per call, uniform.
// Result (oy, ox, od) is computed redundantly by EVERY lane of the cohort
// (identical fp ops on identical LDS data -> bitwise identical).
// ---------------------------------------------------------------------------
template<int NL>
__device__ __forceinline__ void do_level(const float* __restrict__ simg,
                                         const float* __restrict__ dimg, int H,
                                         int ty, int tx, float pary, float parx, bool first,
                                         float* win, float* st, float* dist, int lt,
                                         float& roy, float& rox, float& rod) {
    constexpr int G    = NL / 16;   // lanes per dy-group
    constexpr int ROWS = 16 / G;    // SSD rows per lane

    float dyf = 0.f, dxf = 0.f;
    if (!first) {
        float iy = (float)(ty * 16), ix = (float)(tx * 16);
        // _inherit: round(clip(2*par + i, 0, H-16) - i), half-to-even (rintf).
        dyf = rintf(fminf(fmaxf(2.f * pary + iy, 0.f), (float)(H - 16)) - iy);
        dxf = rintf(fminf(fmaxf(2.f * parx + ix, 0.f), (float)(H - 16)) - ix);
    }
    const int ioy = (int)dyf, iox = (int)dxf;
    const int y0 = ty * 16 + ioy - 5;
    const int x0 = tx * 16 + iox - 5;

    for (int idx = lt; idx < 676; idx += NL) {
        int r = idx / 26, c = idx - r * 26;
        int gy = min(max(y0 + r, 0), H - 1);
        int gx = min(max(x0 + c, 0), H - 1);
        win[r * 28 + c] = dimg[gy * H + gx];
    }
    if (NL == 64 || lt < 64) {
        int r = (lt & 63) >> 2, q = lt & 3;
        const float4* srow = (const float4*)(simg + (size_t)(ty * 16 + r) * H + tx * 16);
        ((float4*)&st[r * 16])[q] = srow[q];
    }
    __syncthreads();   // B1

    const int dy = lt / G;
    if (dy < 11) {
        float acc[11];
        #pragma unroll
        for (int q = 0; q < 11; ++q) acc[q] = 0.f;
        #pragma unroll
        for (int rr = 0; rr < ROWS; ++rr) {
            const int i = (lt & (G - 1)) * ROWS + rr;
            float w[28], s[16];
            const float4* wp = (const float4*)&win[(dy + i) * 28];
            #pragma unroll
            for (int q = 0; q < 7; ++q) ((float4*)w)[q] = wp[q];
            const float4* sp = (const float4*)&st[i * 16];
            #pragma unroll
            for (int q = 0; q < 4; ++q) ((float4*)s)[q] = sp[q];
            #pragma unroll
            for (int dx = 0; dx < 11; ++dx) {
                #pragma unroll
                for (int j = 0; j < 16; ++j) {
                    float d = w[dx + j] - s[j];
                    acc[dx] = fmaf(d, d, acc[dx]);
                }
            }
        }
        // reduce over G-lane row groups (within-wave shfl_xor)
        #pragma unroll
        for (int m = 1; m <= G / 2; m <<= 1) {
            #pragma unroll
            for (int dx = 0; dx < 11; ++dx) acc[dx] += __shfl_xor(acc[dx], m);
        }
        if ((lt & (G - 1)) == 0) {
            float ay = (float)(dy - 5) * (1.f / 11.f);
            #pragma unroll
            for (int dx = 0; dx < 11; ++dx) {
                float ax = (float)(dx - 5) * (1.f / 11.f);
                dist[dy * 11 + dx] = acc[dx] * (1.f / 256.f) + 0.1f * (ay * ay + ax * ax);
            }
        }
    }
    __syncthreads();   // B2

    // Redundant per-lane argmin over central 9x9 (first occurrence on ties).
    const int l = lt & 63;
    float bv; int bk;
    {
        int k = l;                                    // 0..63 < 81 always
        int py = k / 9, px = k - (k / 9) * 9;
        bv = dist[(py + 1) * 11 + (px + 1)]; bk = k;
        k = l + 64;
        if (k < 81) {
            py = k / 9; px = k - (k / 9) * 9;
            float d = dist[(py + 1) * 11 + (px + 1)];
            if (d < bv) { bv = d; bk = k; }           // strict: tie keeps smaller k
        }
    }
    #pragma unroll
    for (int m = 1; m <= 32; m <<= 1) {
        float ov = __shfl_xor(bv, m);
        int   ok = __shfl_xor(bk, m);
        if (ov < bv || (ov == bv && ok < bk)) { bv = ov; bk = ok; }
    }
    // Redundant per-lane subpixel refine (broadcast LDS reads).
    {
        int py = bk / 9, px = bk - (bk / 9) * 9;
        float y00 = dist[(py + 0) * 11 + (px + 0)], y01 = dist[(py + 0) * 11 + (px + 1)], y02 = dist[(py + 0) * 11 + (px + 2)];
        float y10 = dist[(py + 1) * 11 + (px + 0)], y11 = dist[(py + 1) * 11 + (px + 1)], y12 = dist[(py + 1) * 11 + (px + 2)];
        float y20 = dist[(py + 2) * 11 + (px + 0)], y21 = dist[(py + 2) * 11 + (px + 1)], y22 = dist[(py + 2) * 11 + (px + 2)];

        float a11 = (y00 - 2.f * y01 + y02 + 2.f * y10 - 4.f * y11 + 2.f * y12 + y20 - 2.f * y21 + y22) * 0.25f;
        a11 = fmaxf(a11, 0.f);
        float a22 = (y00 + 2.f * y01 + y02 - 2.f * y10 - 4.f * y11 - 2.f * y12 + y20 + 2.f * y21 + y22) * 0.25f;
        a22 = fmaxf(a22, 0.f);
        float a12 = (y00 - y02 - y20 + y22) * 0.25f;
        float b1  = (-y00 + y02 - 2.f * y10 + 2.f * y12 - y20 + y22) * 0.125f;
        float b2  = (-y00 - 2.f * y01 - y02 + y20 + 2.f * y21 + y22) * 0.125f;

        float det  = a11 * a22 - a12 * a12;
        float a12z = (det < 0.f) ? 0.f : a12;
        float mu_x = -(a22 * b1 - a12z * b2) / det;   // inf/nan when det==0 -> filtered
        float mu_y = -(a11 * b2 - a12z * b1) / det;
        float mu_len = sqrtf(mu_x * mu_x + mu_y * mu_y);
        float addx = (mu_len < 1.f) ? mu_x : 0.f;     // NaN -> false, matches jnp.where
        float addy = (mu_len < 1.f) ? mu_y : 0.f;

        roy = dyf + (float)(py - 4) + addy;
        rox = dxf + (float)(px - 4) + addx;
        rod = bv;
    }
}

// ---------------------------------------------------------------------------
// K2: one block per S1 tile (1024 blocks, 256 thr). Rounds: S3,S2,S1 at full
// width (NL=256, shared slot-0 LDS), then ONE round of all 4 S0 children in
// 4 wave-slots (NL=64, slot-private LDS) with fused pixel expand.
// Serial chain depth = 4 (baseline was 5); zero added redundancy.
// LDS: 4 x (728 win + 256 st + 128 dist) = 4448 fl = 17.8 KB; 4 blocks/CU.
// ---------------------------------------------------------------------------
__global__ void __launch_bounds__(256, 4)
step_chain_kernel(const float* __restrict__ src, const float* __restrict__ dst,
                  const float* __restrict__ ws, float* __restrict__ out) {
    __shared__ float smem[4448];

    const float* sL1 = ws;
    const float* dL1 = sL1 + 4 * 65536;
    const float* sL2 = dL1 + 4 * 65536;
    const float* dL2 = sL2 + 4 * 16384;
    const float* sL3 = dL2 + 4 * 16384;
    const float* dL3 = sL3 + 4 * 4096;

    const int gid = blockIdx.x;
    const int b   = gid >> 8;
    const int ty1 = (gid >> 4) & 15;
    const int tx1 = gid & 15;
    const int t    = threadIdx.x;
    const int slot = t >> 6;        // 0..3 == wave id
    const int s_t  = t & 63;

    // LDS carve by offset arithmetic. float4 bases 16B-aligned:
    // win at slot*728 (728*4B=182*16B), st at 2912+slot*256, dist at 3936+slot*128.
    float* win0  = smem;
    float* st0   = smem + 2912;
    float* dist0 = smem + 3936;
    float* winH  = smem + slot * 728;
    float* stH   = smem + 2912 + slot * 256;
    float* distH = smem + 3936 + slot * 128;

    const float* s0 = src + (size_t)b * 262144; const float* d0 = dst + (size_t)b * 262144;
    const float* s1 = sL1 + (size_t)b * 65536;  const float* d1 = dL1 + (size_t)b * 65536;
    const float* s2 = sL2 + (size_t)b * 16384;  const float* d2 = dL2 + (size_t)b * 16384;
    const float* s3 = sL3 + (size_t)b * 4096;   const float* d3 = dL3 + (size_t)b * 4096;

    float oy, ox, od;
    do_level<256>(s3, d3,  64, ty1 >> 2, tx1 >> 2, 0.f, 0.f, true,
                  win0, st0, dist0, t, oy, ox, od);
    do_level<256>(s2, d2, 128, ty1 >> 1, tx1 >> 1, oy, ox, false,
                  win0, st0, dist0, t, oy, ox, od);
    do_level<256>(s1, d1, 256, ty1,      tx1,      oy, ox, false,
                  win0, st0, dist0, t, oy, ox, od);

    // All 4 S0 children in one round: slot -> child (slot>>1, slot&1).
    const int ty0 = 2 * ty1 + (slot >> 1), tx0 = 2 * tx1 + (slot & 1);
    do_level<64>(s0, d0, 512, ty0, tx0, oy, ox, false,
                 winH, stH, distH, s_t, oy, ox, od);

    // Fused expand: every lane of the slot holds identical (oy,ox,od).
    // 256 px per tile, 4 px per lane (float4-aligned).
    int r = s_t >> 2, c = (s_t & 3) * 4;
    int pyy = ty0 * 16 + r, pxx = tx0 * 16 + c;
    size_t pi = ((size_t)(b * 512 + pyy)) * 512 + pxx;   // pixel index, %4 == 0
    float4 o4; o4.x = oy; o4.y = ox; o4.z = oy; o4.w = ox;
    ((float4*)out)[(pi >> 1)]     = o4;   // px pi, pi+1
    ((float4*)out)[(pi >> 1) + 1] = o4;   // px pi+2, pi+3
    float4 dd4; dd4.x = od; dd4.y = od; dd4.z = od; dd4.w = od;
    *(float4*)(out + (size_t)NPIX * 2 + pi) = dd4;
}

extern "C" void kernel_launch(void* const* d_in, const int* in_sizes, int n_in,
                              void* d_out, int out_size, void* d_ws, size_t ws_size,
                              hipStream_t stream) {
    const float* src = (const float*)d_in[0];   // (4,1,512,512)
    const float* dst = (const float*)d_in[1];   // (4,1,512,512)
    float* out = (float*)d_out;                  // offsets (NPIX*2) ++ dist (NPIX)
    float* ws  = (float*)d_ws;                   // pyramid levels, 2.75 MB

    hipLaunchKernelGGL(pyramid_kernel, dim3(16, 16, 8), dim3(256), 0, stream, src, dst, ws);
    hipLaunchKernelGGL(step_chain_kernel, dim3(1024), dim3(256), 0, stream, src, dst, ws, out);
}

// Round 9
// 111.122 us; speedup vs baseline: 1.7217x; 1.1015x over previous
//
#include <hip/hip_runtime.h>

// HDR+ align, 2-kernel version, round 12.
// R11 post-mortem: NL=64/ROWS=4 S0 slots spilled (WRITE 45.5MB vs 13.7 logical,
// +54MB scratch traffic) -> K2 51.5us. Every deviation from R5's SSD codegen
// shape (1-row FULL / 2-row half, 64 VGPR) has lost. This round keeps that
// shape bit-identical and removes serial LATENCY only:
//  - S0: both halves' windows loaded up-front into separate LDS (they depend
//    only on the S1 result); SSD-A -> bar -> SSD-B (barrier bounds register
//    peak to the proven single-SSD shape). One fewer load-latency round.
//  - All src-tile (st) loads for S3/S2/S1/S0x4 issued at kernel entry
//    (addresses independent of offsets); complete under S3's first barrier.
// Constants: T=16, SR=4, PADD=1, SS=11, SSC=9, WIN=26, SW=0.1, GR=2, batch 4, 512x512.

#define NB 4
#define NPIX (NB * 512 * 512)

// Composite 1D tap of (normalized gaussian sigma=1 r=2) followed by avg-pool-2.
constexpr float H6[6] = {
    0.027244342f, 0.149345013f, 0.323410645f,
    0.323410645f, 0.149345013f, 0.027244342f
};

// ---------------------------------------------------------------------------
// K1: pyramid. One block = 4x4 region of L3 (covers 32x32 L0). Grid (16,16,8).
// (Byte-identical to the 112.29us-verified version.)
// ---------------------------------------------------------------------------
__global__ void __launch_bounds__(256, 4)
pyramid_kernel(const float* __restrict__ src, const float* __restrict__ dst,
               float* __restrict__ ws) {
    __shared__ float smem[5520];
    float* patch = smem;            // 60 rows, stride 64
    float* tmpH1 = smem + 3840;     // 60 rows, stride 28
    float* l1    = smem;            // 28 rows, stride 28
    float* tmpH2 = smem + 784;      // 28 rows, stride 12
    float* l2    = smem + 1120;     // 12 rows, stride 12
    float* tmpH3 = smem + 1264;     // 12 rows, stride 4

    float* sL1 = ws;
    float* dL1 = sL1 + 4 * 65536;
    float* sL2 = dL1 + 4 * 65536;
    float* dL2 = sL2 + 4 * 16384;
    float* sL3 = dL2 + 4 * 16384;
    float* dL3 = sL3 + 4 * 4096;

    const int bx = blockIdx.x, by = blockIdx.y, z = blockIdx.z;
    const int t = threadIdx.x;
    const float* in = (z < 4) ? (src + (size_t)z * 262144) : (dst + (size_t)(z - 4) * 262144);
    float* oL1 = ((z < 4) ? sL1 : dL1) + (size_t)(z & 3) * 65536;
    float* oL2 = ((z < 4) ? sL2 : dL2) + (size_t)(z & 3) * 16384;
    float* oL3 = ((z < 4) ? sL3 : dL3) + (size_t)(z & 3) * 4096;

    // P0: 60x60 L0 patch at (by*32-14, bx*32-14), zero OOB (conv zero-pad).
    {
        const int oy = by * 32 - 14, ox = bx * 32 - 14;
        for (int idx = t; idx < 3600; idx += 256) {
            int r = idx / 60, c = idx - r * 60;
            int gy = oy + r, gx = ox + c;
            float v = 0.f;
            if ((unsigned)gy < 512u && (unsigned)gx < 512u) v = in[gy * 512 + gx];
            patch[r * 64 + c] = v;
        }
    }
    __syncthreads();
    // P1: horizontal -> tmpH1[60][28]
    for (int idx = t; idx < 1680; idx += 256) {
        int r = idx / 28, v = idx - r * 28;
        const float* p = &patch[r * 64 + 2 * v];
        float a = 0.f;
        #pragma unroll
        for (int bq = 0; bq < 6; ++bq) a = fmaf(H6[bq], p[bq], a);
        tmpH1[r * 28 + v] = a;
    }
    __syncthreads();
    // P2: vertical -> l1[28][28]; zero if L1 coord OOB (per-level zero-pad).
    {
        const int oy = by * 16 - 6, ox = bx * 16 - 6;
        for (int idx = t; idx < 784; idx += 256) {
            int u = idx / 28, v = idx - u * 28;
            float a = 0.f;
            int y1 = oy + u, x1 = ox + v;
            if ((unsigned)y1 < 256u && (unsigned)x1 < 256u) {
                #pragma unroll
                for (int bq = 0; bq < 6; ++bq) a = fmaf(H6[bq], tmpH1[(2 * u + bq) * 28 + v], a);
            }
            l1[u * 28 + v] = a;
        }
    }
    __syncthreads();
    // P3: write canonical L1 16x16 + horizontal -> tmpH2[28][12]
    {
        int u = t >> 4, v = t & 15;
        oL1[(by * 16 + u) * 256 + bx * 16 + v] = l1[(6 + u) * 28 + 6 + v];
    }
    for (int idx = t; idx < 336; idx += 256) {
        int r = idx / 12, v = idx - r * 12;
        const float* p = &l1[r * 28 + 2 * v];
        float a = 0.f;
        #pragma unroll
        for (int bq = 0; bq < 6; ++bq) a = fmaf(H6[bq], p[bq], a);
        tmpH2[r * 12 + v] = a;
    }
    __syncthreads();
    // P4: vertical -> l2[12][12]; zero if L2 coord OOB.
    {
        const int oy = by * 8 - 2, ox = bx * 8 - 2;
        if (t < 144) {
            int u = t / 12, v = t - u * 12;
            float a = 0.f;
            int y2 = oy + u, x2 = ox + v;
            if ((unsigned)y2 < 128u && (unsigned)x2 < 128u) {
                #pragma unroll
                for (int bq = 0; bq < 6; ++bq) a = fmaf(H6[bq], tmpH2[(2 * u + bq) * 12 + v], a);
            }
            l2[u * 12 + v] = a;
        }
    }
    __syncthreads();
    // P5: write canonical L2 8x8 + horizontal -> tmpH3[12][4]
    if (t < 64) {
        int u = t >> 3, v = t & 7;
        oL2[(by * 8 + u) * 128 + bx * 8 + v] = l2[(2 + u) * 12 + 2 + v];
    } else if (t < 112) {
        int idx = t - 64;
        int r = idx >> 2, v = idx & 3;
        const float* p = &l2[r * 12 + 2 * v];
        float a = 0.f;
        #pragma unroll
        for (int bq = 0; bq < 6; ++bq) a = fmaf(H6[bq], p[bq], a);
        tmpH3[r * 4 + v] = a;
    }
    __syncthreads();
    // P6: vertical -> L3 4x4, write global.
    if (t < 16) {
        int u = t >> 2, v = t & 3;
        float a = 0.f;
        #pragma unroll
        for (int bq = 0; bq < 6; ++bq) a = fmaf(H6[bq], tmpH3[(2 * u + bq) * 4 + v], a);
        oL3[(by * 4 + u) * 64 + bx * 4 + v] = a;
    }
}

// ---------------------------------------------------------------------------
// K2 helpers (bit-identical math to the proven R5 paths).
// ---------------------------------------------------------------------------
__device__ __forceinline__ void inherit_off(int ty, int tx, int H,
                                            float pary, float parx,
                                            float& dyf, float& dxf) {
    float iy = (float)(ty * 16), ix = (float)(tx * 16);
    // _inherit: round(clip(2*par + i, 0, H-16) - i), half-to-even (rintf).
    dyf = rintf(fminf(fmaxf(2.f * pary + iy, 0.f), (float)(H - 16)) - iy);
    dxf = rintf(fminf(fmaxf(2.f * parx + ix, 0.f), (float)(H - 16)) - ix);
}

template<int NL>
__device__ __forceinline__ void load_win(const float* __restrict__ dimg, int H,
                                         int y0, int x0, float* win, int lt) {
    for (int idx = lt; idx < 676; idx += NL) {
        int r = idx / 26, c = idx - r * 26;
        int gy = min(max(y0 + r, 0), H - 1);
        int gx = min(max(x0 + c, 0), H - 1);
        win[r * 28 + c] = dimg[gy * H + gx];
    }
}

// SSD + dist write. FULL: 1 row/lane, 16-lane dy-groups (lt in [0,256)).
// !FULL: 2 rows/lane, 8-lane dy-groups (lt in [0,128)). No barriers inside.
template<bool FULL>
__device__ __forceinline__ void ssd_dist(const float* win, const float* st,
                                         float* dist, int lt) {
    const int dy = FULL ? (lt >> 4) : (lt >> 3);
    if (dy < 11) {
        float acc[11];
        #pragma unroll
        for (int q = 0; q < 11; ++q) acc[q] = 0.f;
        constexpr int ROWS = FULL ? 1 : 2;
        #pragma unroll
        for (int rr = 0; rr < ROWS; ++rr) {
            const int i = FULL ? (lt & 15) : ((lt & 7) * 2 + rr);
            float w[28], s[16];
            const float4* wp = (const float4*)&win[(dy + i) * 28];
            #pragma unroll
            for (int q = 0; q < 7; ++q) ((float4*)w)[q] = wp[q];
            const float4* sp = (const float4*)&st[i * 16];
            #pragma unroll
            for (int q = 0; q < 4; ++q) ((float4*)s)[q] = sp[q];
            #pragma unroll
            for (int dx = 0; dx < 11; ++dx) {
                #pragma unroll
                for (int j = 0; j < 16; ++j) {
                    float d = w[dx + j] - s[j];
                    acc[dx] = fmaf(d, d, acc[dx]);
                }
            }
        }
        constexpr int MMAX = FULL ? 8 : 4;
        #pragma unroll
        for (int m = 1; m <= MMAX; m <<= 1) {
            #pragma unroll
            for (int dx = 0; dx < 11; ++dx) acc[dx] += __shfl_xor(acc[dx], m);
        }
        const bool leader = FULL ? ((lt & 15) == 0) : ((lt & 7) == 0);
        if (leader) {
            float ay = (float)(dy - 5) * (1.f / 11.f);
            #pragma unroll
            for (int dx = 0; dx < 11; ++dx) {
                float ax = (float)(dx - 5) * (1.f / 11.f);
                dist[dy * 11 + dx] = acc[dx] * (1.f / 256.f) + 0.1f * (ay * ay + ax * ax);
            }
        }
    }
}

// Redundant per-lane argmin over central 9x9 + subpixel refine (baseline).
__device__ __forceinline__ void argmin_refine(const float* dist, int lt,
                                              float dyf, float dxf,
                                              float& roy, float& rox, float& rod) {
    const int l = lt & 63;
    float bv; int bk;
    {
        int k = l;                                    // 0..63 < 81 always
        int py = k / 9, px = k - (k / 9) * 9;
        bv = dist[(py + 1) * 11 + (px + 1)]; bk = k;
        k = l + 64;
        if (k < 81) {
            py = k / 9; px = k - (k / 9) * 9;
            float d = dist[(py + 1) * 11 + (px + 1)];
            if (d < bv) { bv = d; bk = k; }           // strict: tie keeps smaller k
        }
    }
    #pragma unroll
    for (int m = 1; m <= 32; m <<= 1) {
        float ov = __shfl_xor(bv, m);
        int   ok = __shfl_xor(bk, m);
        if (ov < bv || (ov == bv && ok < bk)) { bv = ov; bk = ok; }
    }
    {
        int py = bk / 9, px = bk - (bk / 9) * 9;
        float y00 = dist[(py + 0) * 11 + (px + 0)], y01 = dist[(py + 0) * 11 + (px + 1)], y02 = dist[(py + 0) * 11 + (px + 2)];
        float y10 = dist[(py + 1) * 11 + (px + 0)], y11 = dist[(py + 1) * 11 + (px + 1)], y12 = dist[(py + 1) * 11 + (px + 2)];
        float y20 = dist[(py + 2) * 11 + (px + 0)], y21 = dist[(py + 2) * 11 + (px + 1)], y22 = dist[(py + 2) * 11 + (px + 2)];

        float a11 = (y00 - 2.f * y01 + y02 + 2.f * y10 - 4.f * y11 + 2.f * y12 + y20 - 2.f * y21 + y22) * 0.25f;
        a11 = fmaxf(a11, 0.f);
        float a22 = (y00 + 2.f * y01 + y02 - 2.f * y10 - 4.f * y11 - 2.f * y12 + y20 + 2.f * y21 + y22) * 0.25f;
        a22 = fmaxf(a22, 0.f);
        float a12 = (y00 - y02 - y20 + y22) * 0.25f;
        float b1  = (-y00 + y02 - 2.f * y10 + 2.f * y12 - y20 + y22) * 0.125f;
        float b2  = (-y00 - 2.f * y01 - y02 + y20 + 2.f * y21 + y22) * 0.125f;

        float det  = a11 * a22 - a12 * a12;
        float a12z = (det < 0.f) ? 0.f : a12;
        float mu_x = -(a22 * b1 - a12z * b2) / det;   // inf/nan when det==0 -> filtered
        float mu_y = -(a11 * b2 - a12z * b1) / det;
        float mu_len = sqrtf(mu_x * mu_x + mu_y * mu_y);
        float addx = (mu_len < 1.f) ? mu_x : 0.f;     // NaN -> false, matches jnp.where
        float addy = (mu_len < 1.f) ? mu_y : 0.f;

        roy = dyf + (float)(py - 4) + addy;
        rox = dxf + (float)(px - 4) + addx;
        rod = bv;
    }
}

// ---------------------------------------------------------------------------
// K2: one block per S1 tile (1024 blocks, 256 thr, 4 blocks/CU).
// Entry: issue ALL st loads (S3,S2,S1,S0x4 -- offset-independent).
// Rounds: S3,S2,S1 full-width (win_c shared); S0: both halves' windows loaded
// up-front per 128-thr slot, SSD-A -> bar -> SSD-B -> bar -> argmins+writes.
// Serial load-latency rounds: 4 (baseline 5); barriers: 9 (baseline 10).
// LDS map (floats, all float4 bases 16B-aligned):
//   win_c 0..728 | win0[s][h] 728+(2s+h)*728 ..3640 | dist_c 3640..3768 |
//   dist0[s][h] 3768+(2s+h)*128 ..4280 | stL3 4280 | stL2 4536 | stL1 4792 |
//   st0[c] 5048+c*256 ..6072.  Total 6072 fl = 24.3 KB; 4 blocks/CU = 97 KB.
// ---------------------------------------------------------------------------
__global__ void __launch_bounds__(256, 4)
step_chain_kernel(const float* __restrict__ src, const float* __restrict__ dst,
                  const float* __restrict__ ws, float* __restrict__ out) {
    __shared__ float smem[6072];

    const float* sL1 = ws;
    const float* dL1 = sL1 + 4 * 65536;
    const float* sL2 = dL1 + 4 * 65536;
    const float* dL2 = sL2 + 4 * 16384;
    const float* sL3 = dL2 + 4 * 16384;
    const float* dL3 = sL3 + 4 * 4096;

    const int gid = blockIdx.x;
    const int b   = gid >> 8;
    const int ty1 = (gid >> 4) & 15;
    const int tx1 = gid & 15;
    const int t    = threadIdx.x;
    const int slot = t >> 7;        // 0..1
    const int s_t  = t & 127;

    float* win_c = smem;
    float* dist_c = smem + 3640;
    float* winA  = smem + 728 + (2 * slot + 0) * 728;
    float* winB  = smem + 728 + (2 * slot + 1) * 728;
    float* distA = smem + 3768 + (2 * slot + 0) * 128;
    float* distB = smem + 3768 + (2 * slot + 1) * 128;
    float* stL3 = smem + 4280;
    float* stL2 = smem + 4536;
    float* stL1 = smem + 4792;
    float* st0  = smem + 5048;      // [4][256], child c = 2*half + slot

    const float* s0 = src + (size_t)b * 262144; const float* d0 = dst + (size_t)b * 262144;
    const float* s1 = sL1 + (size_t)b * 65536;  const float* d1 = dL1 + (size_t)b * 65536;
    const float* s2 = sL2 + (size_t)b * 16384;  const float* d2 = dL2 + (size_t)b * 16384;
    const float* s3 = sL3 + (size_t)b * 4096;   const float* d3 = dL3 + (size_t)b * 4096;

    // ---- Entry: issue all offset-independent src-tile loads ----
    {
        const int it = t & 63, r = it >> 2, q = t & 3;
        // S0: 4 children x 64 float4 items = exactly 256 threads.
        const int c = t >> 6;
        const int ty0 = 2 * ty1 + (c >> 1), tx0 = 2 * tx1 + (c & 1);
        const float4* p0 = (const float4*)(s0 + (size_t)(ty0 * 16 + r) * 512 + tx0 * 16);
        ((float4*)&st0[c * 256 + r * 16])[q] = p0[q];
        if (t < 64) {
            const float4* p = (const float4*)(s3 + (size_t)((ty1 >> 2) * 16 + r) * 64 + (tx1 >> 2) * 16);
            ((float4*)&stL3[r * 16])[q] = p[q];
        } else if (t < 128) {
            const float4* p = (const float4*)(s2 + (size_t)((ty1 >> 1) * 16 + r) * 128 + (tx1 >> 1) * 16);
            ((float4*)&stL2[r * 16])[q] = p[q];
        } else if (t < 192) {
            const float4* p = (const float4*)(s1 + (size_t)(ty1 * 16 + r) * 256 + tx1 * 16);
            ((float4*)&stL1[r * 16])[q] = p[q];
        }
    }

    float oy, ox, od;
    // ---- S3 (first: offset 0) ----
    {
        load_win<256>(d3, 64, (ty1 >> 2) * 16 - 5, (tx1 >> 2) * 16 - 5, win_c, t);
        __syncthreads();                      // also completes all st preloads
        ssd_dist<true>(win_c, stL3, dist_c, t);
        __syncthreads();
        argmin_refine(dist_c, t, 0.f, 0.f, oy, ox, od);
    }
    // ---- S2 ----
    {
        float dyf, dxf; inherit_off(ty1 >> 1, tx1 >> 1, 128, oy, ox, dyf, dxf);
        load_win<256>(d2, 128, (ty1 >> 1) * 16 + (int)dyf - 5, (tx1 >> 1) * 16 + (int)dxf - 5, win_c, t);
        __syncthreads();
        ssd_dist<true>(win_c, stL2, dist_c, t);
        __syncthreads();
        argmin_refine(dist_c, t, dyf, dxf, oy, ox, od);
    }
    // ---- S1 ----
    {
        float dyf, dxf; inherit_off(ty1, tx1, 256, oy, ox, dyf, dxf);
        load_win<256>(d1, 256, ty1 * 16 + (int)dyf - 5, tx1 * 16 + (int)dxf - 5, win_c, t);
        __syncthreads();
        ssd_dist<true>(win_c, stL1, dist_c, t);
        __syncthreads();
        argmin_refine(dist_c, t, dyf, dxf, oy, ox, od);
    }

    // ---- S0: both halves per slot, windows loaded together ----
    const int tyA = 2 * ty1,     txA = 2 * tx1 + slot;   // half 0
    const int tyB = 2 * ty1 + 1, txB = 2 * tx1 + slot;   // half 1
    float dyfA, dxfA, dyfB, dxfB;
    inherit_off(tyA, txA, 512, oy, ox, dyfA, dxfA);
    inherit_off(tyB, txB, 512, oy, ox, dyfB, dxfB);
    load_win<128>(d0, 512, tyA * 16 + (int)dyfA - 5, txA * 16 + (int)dxfA - 5, winA, s_t);
    load_win<128>(d0, 512, tyB * 16 + (int)dyfB - 5, txB * 16 + (int)dxfB - 5, winB, s_t);
    __syncthreads();
    ssd_dist<false>(winA, st0 + (0 * 2 + slot) * 256, distA, s_t);
    __syncthreads();   // bounds register peak to single-SSD shape (anti-spill)
    ssd_dist<false>(winB, st0 + (1 * 2 + slot) * 256, distB, s_t);
    __syncthreads();

    // ---- argmin + fused pixel expand (2 px/lane per half, float2 writes) ----
    const int r = s_t >> 3, c2 = (s_t & 7) * 2;
    {
        float oyA, oxA, odA;
        argmin_refine(distA, s_t, dyfA, dxfA, oyA, oxA, odA);
        int pyy = tyA * 16 + r, pxx = txA * 16 + c2;
        size_t pi = ((size_t)(b * 512 + pyy)) * 512 + pxx;
        float2 o; o.x = oyA; o.y = oxA;
        ((float2*)out)[pi]     = o;
        ((float2*)out)[pi + 1] = o;
        float2 dd; dd.x = odA; dd.y = odA;
        *(float2*)(out + (size_t)NPIX * 2 + pi) = dd;
    }
    {
        float oyB, oxB, odB;
        argmin_refine(distB, s_t, dyfB, dxfB, oyB, oxB, odB);
        int pyy = tyB * 16 + r, pxx = txB * 16 + c2;
        size_t pi = ((size_t)(b * 512 + pyy)) * 512 + pxx;
        float2 o; o.x = oyB; o.y = oxB;
        ((float2*)out)[pi]     = o;
        ((float2*)out)[pi + 1] = o;
        float2 dd; dd.x = odB; dd.y = odB;
        *(float2*)(out + (size_t)NPIX * 2 + pi) = dd;
    }
}

extern "C" void kernel_launch(void* const* d_in, const int* in_sizes, int n_in,
                              void* d_out, int out_size, void* d_ws, size_t ws_size,
                              hipStream_t stream) {
    const float* src = (const float*)d_in[0];   // (4,1,512,512)
    const float* dst = (const float*)d_in[1];   // (4,1,512,512)
    float* out = (float*)d_out;                  // offsets (NPIX*2) ++ dist (NPIX)
    float* ws  = (float*)d_ws;                   // pyramid levels, 2.75 MB

    hipLaunchKernelGGL(pyramid_kernel, dim3(16, 16, 8), dim3(256), 0, stream, src, dst, ws);
    hipLaunchKernelGGL(step_chain_kernel, dim3(1024), dim3(256), 0, stream, src, dst, ws, out);
}